// Round 4
// baseline (957.539 us; speedup 1.0000x reference)
//
#include <hip/hip_runtime.h>

typedef __attribute__((ext_vector_type(8))) short short8;
typedef __attribute__((ext_vector_type(8))) unsigned short us8;
typedef __attribute__((ext_vector_type(4))) unsigned short us4;
typedef __attribute__((ext_vector_type(4))) float f32x4;

#define FCRIT 3.8415923532

// ---------------- workspace layout (bytes) ----------------
#define OFF_FULL   0u          // double[4][16][2] full-image conv stats
#define OFF_PATCH  1024u       // double[4][64][2] per-layer patch stats
#define OFF_SBUF   8192u       // float[4][4][64][64] logits per layer
#define OFF_BAR    270336u     // barrier counters
#define ZERO_BYTES 270592u
#define OFF_W3H    (1u<<20)              // ushort[3][192][256]
#define OFF_WRH    (OFF_W3H + 294912u)   // ushort[3][256][64]
#define OFF_WFH    (OFF_WRH + 98304u)    // ushort[3][16][256]
#define OFF_QBT    (4u<<20)    // ushort[2][4][4096][64]  Q pixel-major
#define OFF_KB     (8u<<20)    // ushort[2][4][64][4096]  K channel-major
#define OFF_VBT    (12u<<20)   // ushort[2][4][4096][64]  V pixel-major
#define OFF_XB     (16u<<20)   // ushort[2][4][4096][256] patch splits [px][c]
#define OFF_PB     (32u<<20)   // float[4][4][4096][256]  P1..P4 pixel-major

// ---------------- helpers ----------------
static __device__ __forceinline__ unsigned short f2bf(float f) {
  union { float f; unsigned u; } v; v.f = f;
  unsigned r = v.u + 0x7fffu + ((v.u >> 16) & 1u);
  return (unsigned short)(r >> 16);
}
static __device__ __forceinline__ float bf2f(unsigned short h) {
  union { unsigned u; float f; } v; v.u = ((unsigned)h) << 16;
  return v.f;
}
static __device__ __forceinline__ void split2(float v, unsigned short& h, unsigned short& m) {
  h = f2bf(v); float r = v - bf2f(h); m = f2bf(r);
}
static __device__ __forceinline__ double wred(double v) {
#pragma unroll
  for (int off = 32; off > 0; off >>= 1) v += __shfl_down(v, off, 64);
  return v;
}
// device-scope grid barrier; all participating blocks must be co-resident.
static __device__ __forceinline__ void gbar(unsigned* cnt, unsigned target) {
  __syncthreads();
  if (threadIdx.x == 0) {
    __threadfence();
    atomicAdd(cnt, 1u);
    unsigned spins = 0;
    while (__hip_atomic_load(cnt, __ATOMIC_RELAXED, __HIP_MEMORY_SCOPE_AGENT) < target) {
      __builtin_amdgcn_s_sleep(2);
      if (++spins > (1u << 20)) break;   // deadlock bailout: fail, don't hang
    }
    __threadfence();
  }
  __syncthreads();
}

// ---------------- weight conversion: 3-level bf16 splits of W3|Wr|Wf ----------------
__global__ __launch_bounds__(256) void k_wcvt(const float* __restrict__ Wq,
                                              const float* __restrict__ Wk,
                                              const float* __restrict__ Wv,
                                              const float* __restrict__ Wr,
                                              const float* __restrict__ Wf,
                                              char* __restrict__ ws) {
  unsigned short* W3H = (unsigned short*)(ws + OFF_W3H);
  unsigned short* WRH = (unsigned short*)(ws + OFF_WRH);
  unsigned short* WFH = (unsigned short*)(ws + OFF_WFH);
  for (int i = blockIdx.x * 256 + threadIdx.x; i < 69632; i += gridDim.x * 256) {
    float v; unsigned short* dst; int stride;
    if (i < 49152) {
      const int row = i >> 8, col = i & 255;
      v = (row < 64) ? Wq[row * 256 + col]
        : (row < 128) ? Wk[(row - 64) * 256 + col]
                      : Wv[(row - 128) * 256 + col];
      dst = W3H + i; stride = 49152;
    } else if (i < 65536) {
      v = Wr[i - 49152]; dst = WRH + (i - 49152); stride = 16384;
    } else {
      v = Wf[i - 65536]; dst = WFH + (i - 65536); stride = 4096;
    }
    const unsigned short h = f2bf(v); const float r1 = v - bf2f(h);
    const unsigned short m = f2bf(r1); const float r2 = r1 - bf2f(m);
    dst[0] = h; dst[stride] = m; dst[2 * stride] = f2bf(r2);
  }
}

// ---------------- the persistent mega-kernel ----------------
// grid 256 x 256: blocks 0..191 = copy crew (x->out + full conv stats),
// blocks 192..255 = attention crew (4 speculative layers), then global
// barrier -> decision -> patch select/copy.
__global__ __launch_bounds__(256, 1) void k_mega(
    const float* __restrict__ x, const float* __restrict__ bq,
    const float* __restrict__ bk, const float* __restrict__ bv,
    const float* __restrict__ br, const float* __restrict__ bf,
    const float* __restrict__ Wf, float* __restrict__ out,
    char* __restrict__ ws) {
  __shared__ __align__(16) char pool[55296];
  const int t = threadIdx.x;
  const int bid = blockIdx.x;
  double* fullS  = (double*)(ws + OFF_FULL);
  double* patchS = (double*)(ws + OFF_PATCH);
  float* Sb = (float*)(ws + OFF_SBUF);
  unsigned* cntA = (unsigned*)(ws + OFF_BAR);
  unsigned* cntG = (unsigned*)(ws + OFF_BAR + 128);
  unsigned short* W3H = (unsigned short*)(ws + OFF_W3H);
  unsigned short* WRH = (unsigned short*)(ws + OFF_WRH);
  unsigned short* WFH = (unsigned short*)(ws + OFF_WFH);
  unsigned short* QBT = (unsigned short*)(ws + OFF_QBT);
  unsigned short* KB  = (unsigned short*)(ws + OFF_KB);
  unsigned short* VBT = (unsigned short*)(ws + OFF_VBT);
  unsigned short* XB  = (unsigned short*)(ws + OFF_XB);
  float* PB = (float*)(ws + OFF_PB);
  const int w = t >> 6, lane = t & 63;
  const int lo16 = lane & 15, hi4 = lane >> 4;

  if (bid < 192) {
    // ================= COPY CREW =================
    float* WfT2 = (float*)pool;                 // 16*257*4
    float* WfT  = (float*)(pool + 16448);       // 256*16*4
    double* sm  = (double*)(pool + 32896);      // [4][16][2]
    for (int r = 0; r < 16; ++r) {
      int idx = r * 256 + t;
      WfT2[(idx >> 8) * 257 + (idx & 255)] = Wf[idx];
    }
    __syncthreads();
    for (int r = 0; r < 16; ++r) {
      int idx = r * 256 + t;
      int c = idx >> 4, o = idx & 15;
      WfT[c * 16 + o] = WfT2[o * 257 + c];
    }
    __syncthreads();
    for (int rp = bid; rp < 512; rp += 192) {
      const int bb = rp >> 7;
      const int r0 = (rp & 127) * 2 + (t >> 7);
      const int col2 = (t & 127) * 2;
      const size_t base = (size_t)bb * 16777216 + (size_t)r0 * 256 + col2;
      const float* xp = x + base;
      float* op = out + base;
      float y0[16], y1[16];
#pragma unroll
      for (int o = 0; o < 16; ++o) { y0[o] = 0.f; y1[o] = 0.f; }
      for (int cb = 0; cb < 32; ++cb) {
        double v[8];
#pragma unroll
        for (int u = 0; u < 8; ++u)
          v[u] = *reinterpret_cast<const double*>(xp + (size_t)(cb * 8 + u) * 65536);
#pragma unroll
        for (int u = 0; u < 8; ++u) {
          __builtin_nontemporal_store(v[u], reinterpret_cast<double*>(op + (size_t)(cb * 8 + u) * 65536));
          const int c = cb * 8 + u;
          float2 f = *reinterpret_cast<const float2*>(&v[u]);
          const float4* wf = reinterpret_cast<const float4*>(&WfT[c * 16]);
          const float4 w0 = wf[0], w1 = wf[1], w2 = wf[2], w3 = wf[3];
          const float wv[16] = {w0.x, w0.y, w0.z, w0.w, w1.x, w1.y, w1.z, w1.w,
                                w2.x, w2.y, w2.z, w2.w, w3.x, w3.y, w3.z, w3.w};
#pragma unroll
          for (int o = 0; o < 16; ++o) {
            y0[o] += wv[o] * f.x;
            y1[o] += wv[o] * f.y;
          }
        }
      }
#pragma unroll 1
      for (int o = 0; o < 16; ++o) {
        const float bo = bf[o];
        const double a0 = (double)(y0[o] + bo), a1 = (double)(y1[o] + bo);
        double s1 = a0 + a1, s2 = a0 * a0 + a1 * a1;
        const double r1 = wred(s1), r2 = wred(s2);
        if (lane == 0) { sm[(w * 16 + o) * 2] = r1; sm[(w * 16 + o) * 2 + 1] = r2; }
      }
      __syncthreads();
      if (t < 32) {
        const int o = t >> 1, wh = t & 1;
        double s = sm[o * 2 + wh] + sm[(16 + o) * 2 + wh] + sm[(32 + o) * 2 + wh] + sm[(48 + o) * 2 + wh];
        unsafeAtomicAdd(&fullS[(bb * 16 + o) * 2 + wh], s);
      }
      __syncthreads();
    }
  } else {
    // ================= ATTENTION CREW (speculative) =================
    const int bid2 = bid - 192;
    const int b = bid2 >> 4;
    const int q16 = bid2 & 15;
    unsigned barSeq = 0;
    for (int layer = 0; layer < 4; ++layer) {
      const float* Pprev = PB + (size_t)(layer - 1) * 4194304;  // valid only layer>0
      const int px0 = q16 * 256;
      // ---- Phase A: convert P_l -> bf16 splits (XB) + ftest conv stats ----
      {
        unsigned short* XhL = (unsigned short*)pool;            // [256][40]
        unsigned short* XmL = (unsigned short*)(pool + 20480);
        const int pxg = px0 + t;
        f32x4 fa[4];
#pragma unroll
        for (int nf = 0; nf < 4; ++nf) fa[nf] = (f32x4)0.f;
        for (int kc = 0; kc < 8; ++kc) {
          const int c0 = kc * 32;
          __syncthreads();
          float vv[32];
          if (layer == 0) {
            const float* xp = x + (size_t)b * 16777216 + (size_t)(192 + (pxg >> 6)) * 256
                              + (192 + (pxg & 63)) + (size_t)c0 * 65536;
#pragma unroll
            for (int u = 0; u < 32; ++u) vv[u] = xp[(size_t)u * 65536];
          } else {
            const float* pp = Pprev + ((size_t)b * 4096 + pxg) * 256 + c0;
#pragma unroll
            for (int u = 0; u < 8; ++u)
              *reinterpret_cast<float4*>(&vv[u * 4]) = reinterpret_cast<const float4*>(pp)[u];
          }
          unsigned short* xh = XB + ((size_t)b * 4096 + pxg) * 256 + c0;
#pragma unroll
          for (int g = 0; g < 4; ++g) {
            us8 hv, mv;
#pragma unroll
            for (int j = 0; j < 8; ++j) {
              unsigned short h, m; split2(vv[g * 8 + j], h, m);
              hv[j] = h; mv[j] = m;
            }
            *(us8*)&XhL[t * 40 + g * 8] = hv;
            *(us8*)&XmL[t * 40 + g * 8] = mv;
            *(us8*)(xh + g * 8) = hv;
            *(us8*)(xh + 4194304 + g * 8) = mv;
          }
          __syncthreads();
          const short8 ah = *(const short8*)(WFH + lo16 * 256 + c0 + hi4 * 8);
          const short8 am = *(const short8*)(WFH + 4096 + lo16 * 256 + c0 + hi4 * 8);
          const short8 al = *(const short8*)(WFH + 8192 + lo16 * 256 + c0 + hi4 * 8);
#pragma unroll
          for (int nf = 0; nf < 4; ++nf) {
            const int pxl = w * 64 + nf * 16 + lo16;
            const short8 bh = *(const short8*)&XhL[pxl * 40 + hi4 * 8];
            const short8 bm = *(const short8*)&XmL[pxl * 40 + hi4 * 8];
            f32x4 c = fa[nf];
            c = __builtin_amdgcn_mfma_f32_16x16x32_bf16(ah, bh, c, 0, 0, 0);
            c = __builtin_amdgcn_mfma_f32_16x16x32_bf16(ah, bm, c, 0, 0, 0);
            c = __builtin_amdgcn_mfma_f32_16x16x32_bf16(am, bh, c, 0, 0, 0);
            c = __builtin_amdgcn_mfma_f32_16x16x32_bf16(am, bm, c, 0, 0, 0);
            c = __builtin_amdgcn_mfma_f32_16x16x32_bf16(al, bh, c, 0, 0, 0);
            fa[nf] = c;
          }
        }
#pragma unroll
        for (int r = 0; r < 4; ++r) {
          const int o = hi4 * 4 + r;
          const float bo = bf[o];
          double s1 = 0.0, s2 = 0.0;
#pragma unroll
          for (int nf = 0; nf < 4; ++nf) {
            const double v = (double)(fa[nf][r] + bo);
            s1 += v; s2 += v * v;
          }
#pragma unroll
          for (int msk = 1; msk < 16; msk <<= 1) {
            s1 += __shfl_xor(s1, msk, 64);
            s2 += __shfl_xor(s2, msk, 64);
          }
          if (lo16 == 0) {
            unsafeAtomicAdd(&patchS[layer * 128 + (b * 16 + o) * 2], s1);
            unsafeAtomicAdd(&patchS[layer * 128 + (b * 16 + o) * 2 + 1], s2);
          }
        }
      }
      gbar(cntA, 64 * (++barSeq));
      // ---- Phase B: QKV = W3 @ P_l; write Q/V pixel-major, K channel-major (bf16 2-lev) ----
      {
        unsigned short* WhL = (unsigned short*)pool;            // [2][192][40]
        unsigned short* XhB = (unsigned short*)(pool + 30720);  // [2][128][40]
        const unsigned short* W3L2 = W3H + 2 * 49152;
        for (int ph = 0; ph < 2; ++ph) {
          f32x4 bacc[12][2];
#pragma unroll
          for (int mf = 0; mf < 12; ++mf)
#pragma unroll
            for (int nf = 0; nf < 2; ++nf) bacc[mf][nf] = (f32x4)0.f;
          for (int kc = 0; kc < 8; ++kc) {
            const int c0 = kc * 32;
            __syncthreads();
#pragma unroll
            for (int lev = 0; lev < 2; ++lev) {
#pragma unroll
              for (int r = 0; r < 3; ++r) {
                const int unit = r * 256 + t;
                const int m = unit >> 2, k8 = (unit & 3) * 8;
                *(us8*)&WhL[lev * 7680 + m * 40 + k8] =
                    *(const us8*)(W3H + lev * 49152 + m * 256 + c0 + k8);
              }
#pragma unroll
              for (int r = 0; r < 2; ++r) {
                const int unit = r * 256 + t;
                const int px = unit >> 2, k8 = (unit & 3) * 8;
                *(us8*)&XhB[lev * 5120 + px * 40 + k8] =
                    *(const us8*)(XB + (size_t)lev * 4194304
                                  + ((size_t)b * 4096 + px0 + ph * 128 + px) * 256 + c0 + k8);
              }
            }
            __syncthreads();
            short8 xbh[2], xbm[2];
#pragma unroll
            for (int nf = 0; nf < 2; ++nf) {
              const int pxl = w * 32 + nf * 16 + lo16;
              xbh[nf] = *(const short8*)&XhB[pxl * 40 + hi4 * 8];
              xbm[nf] = *(const short8*)&XhB[5120 + pxl * 40 + hi4 * 8];
            }
#pragma unroll
            for (int mf = 0; mf < 12; ++mf) {
              const int m = mf * 16 + lo16;
              const short8 wh = *(const short8*)&WhL[m * 40 + hi4 * 8];
              const short8 wm = *(const short8*)&WhL[7680 + m * 40 + hi4 * 8];
              const short8 wl = *(const short8*)(W3L2 + m * 256 + c0 + hi4 * 8);
#pragma unroll
              for (int nf = 0; nf < 2; ++nf) {
                f32x4 c = bacc[mf][nf];
                c = __builtin_amdgcn_mfma_f32_16x16x32_bf16(wh, xbh[nf], c, 0, 0, 0);
                c = __builtin_amdgcn_mfma_f32_16x16x32_bf16(wh, xbm[nf], c, 0, 0, 0);
                c = __builtin_amdgcn_mfma_f32_16x16x32_bf16(wm, xbh[nf], c, 0, 0, 0);
                c = __builtin_amdgcn_mfma_f32_16x16x32_bf16(wm, xbm[nf], c, 0, 0, 0);
                c = __builtin_amdgcn_mfma_f32_16x16x32_bf16(wl, xbh[nf], c, 0, 0, 0);
                bacc[mf][nf] = c;
              }
            }
          }
#pragma unroll
          for (int mf = 0; mf < 12; ++mf) {
            const int m0 = mf * 16 + hi4 * 4;
            const float* bias = (m0 < 64) ? bq + m0 : (m0 < 128) ? bk + (m0 - 64) : bv + (m0 - 128);
#pragma unroll
            for (int nf = 0; nf < 2; ++nf) {
              const int pxg = px0 + ph * 128 + w * 32 + nf * 16 + lo16;
              us4 hv, mv;
#pragma unroll
              for (int r = 0; r < 4; ++r) {
                unsigned short h, m;
                split2(bacc[mf][nf][r] + bias[r], h, m);
                hv[r] = h; mv[r] = m;
              }
              if (mf < 4) {
                const size_t o = ((size_t)b * 4096 + pxg) * 64 + m0;
                *(us4*)(QBT + o) = hv;
                *(us4*)(QBT + 1048576 + o) = mv;
              } else if (mf < 8) {
#pragma unroll
                for (int r = 0; r < 4; ++r) {
                  const size_t o = ((size_t)b * 64 + (m0 - 64 + r)) * 4096 + pxg;
                  KB[o] = hv[r];
                  KB[1048576 + o] = mv[r];
                }
              } else {
                const size_t o = ((size_t)b * 4096 + pxg) * 64 + (m0 - 128);
                *(us4*)(VBT + o) = hv;
                *(us4*)(VBT + 1048576 + o) = mv;
              }
            }
          }
        }
      }
      gbar(cntA, 64 * (++barSeq));
      // ---- Phase C: S = Q @ K' (4 m-chunks per block, fp32 atomic accumulate) ----
      {
        unsigned short* At = (unsigned short*)pool;            // [2][64][72]
        unsigned short* Bt = (unsigned short*)(pool + 18432);  // [2][64][72]
        f32x4 cacc[4];
#pragma unroll
        for (int mf = 0; mf < 4; ++mf) cacc[mf] = (f32x4)0.f;
        for (int mcl = 0; mcl < 4; ++mcl) {
          const int mc = q16 * 4 + mcl;
          __syncthreads();
          {
            const int r2 = t >> 2, ig = (t & 3) * 16;
#pragma unroll
            for (int lev = 0; lev < 2; ++lev) {
              const size_t qb = (size_t)lev * 1048576 + ((size_t)b * 4096 + mc * 64 + r2) * 64 + ig;
              const us8 v0 = *(const us8*)(QBT + qb);
              const us8 v1 = *(const us8*)(QBT + qb + 8);
#pragma unroll
              for (int ii = 0; ii < 8; ++ii) {
                At[lev * 4608 + (ig + ii) * 72 + r2] = v0[ii];
                At[lev * 4608 + (ig + 8 + ii) * 72 + r2] = v1[ii];
              }
            }
            const int p0 = t * 16;
            const int jj0 = p0 & 63, rr = p0 >> 6;
#pragma unroll
            for (int lev = 0; lev < 2; ++lev) {
              const size_t kb = (size_t)lev * 1048576 + ((size_t)b * 64 + mc) * 4096 + p0;
              const us8 v0 = *(const us8*)(KB + kb);
              const us8 v1 = *(const us8*)(KB + kb + 8);
#pragma unroll
              for (int ii = 0; ii < 8; ++ii) {
                Bt[lev * 4608 + (jj0 + ii) * 72 + rr] = v0[ii];
                Bt[lev * 4608 + (jj0 + 8 + ii) * 72 + rr] = v1[ii];
              }
            }
          }
          __syncthreads();
#pragma unroll
          for (int kc = 0; kc < 2; ++kc) {
            const short8 bh = *(const short8*)&Bt[(w * 16 + lo16) * 72 + kc * 32 + hi4 * 8];
            const short8 bm = *(const short8*)&Bt[4608 + (w * 16 + lo16) * 72 + kc * 32 + hi4 * 8];
#pragma unroll
            for (int mf = 0; mf < 4; ++mf) {
              const short8 qh = *(const short8*)&At[(mf * 16 + lo16) * 72 + kc * 32 + hi4 * 8];
              const short8 qm = *(const short8*)&At[4608 + (mf * 16 + lo16) * 72 + kc * 32 + hi4 * 8];
              f32x4 c = cacc[mf];
              c = __builtin_amdgcn_mfma_f32_16x16x32_bf16(qh, bh, c, 0, 0, 0);
              c = __builtin_amdgcn_mfma_f32_16x16x32_bf16(qh, bm, c, 0, 0, 0);
              c = __builtin_amdgcn_mfma_f32_16x16x32_bf16(qm, bh, c, 0, 0, 0);
              c = __builtin_amdgcn_mfma_f32_16x16x32_bf16(qm, bm, c, 0, 0, 0);
              cacc[mf] = c;
            }
          }
        }
        float* Sl = Sb + ((size_t)layer * 4 + b) * 4096;
#pragma unroll
        for (int mf = 0; mf < 4; ++mf)
#pragma unroll
          for (int r = 0; r < 4; ++r)
            unsafeAtomicAdd(&Sl[(mf * 16 + hi4 * 4 + r) * 64 + w * 16 + lo16], cacc[mf][r]);
      }
      gbar(cntA, 64 * (++barSeq));
      // ---- Phase D: softmax + A = wts@V + P_{l+1} = Wr@A + br + P_l ----
      {
        unsigned short* wtsL = (unsigned short*)pool;            // [2][64][72]
        unsigned short* AbT  = (unsigned short*)(pool + 18432);  // [2][128][72]
        float* Sf = (float*)(pool + 18432);                      // [64][68] (dead before AbT)
        const float* Sl = Sb + ((size_t)layer * 4 + b) * 4096;
        {
          const int i2 = t >> 2, jg = (t & 3) * 16;
#pragma unroll
          for (int u = 0; u < 4; ++u) {
            const float4 v = *(const float4*)(Sl + i2 * 64 + jg + u * 4);
            Sf[(jg + u * 4 + 0) * 68 + i2] = v.x;
            Sf[(jg + u * 4 + 1) * 68 + i2] = v.y;
            Sf[(jg + u * 4 + 2) * 68 + i2] = v.z;
            Sf[(jg + u * 4 + 3) * 68 + i2] = v.w;
          }
        }
        __syncthreads();
        if (t < 64) {
          float* rowp = &Sf[t * 68];
          float mx = -1e30f;
#pragma unroll
          for (int i = 0; i < 64; ++i) mx = fmaxf(mx, rowp[i]);
          float sum = 0.f;
#pragma unroll
          for (int i = 0; i < 64; ++i) {
            const float e = __expf(rowp[i] - mx);
            rowp[i] = e; sum += e;
          }
          const float inv = 1.f / sum;
#pragma unroll
          for (int i = 0; i < 64; ++i) rowp[i] *= inv;
        }
        __syncthreads();
        {
          const int i2 = t >> 2, jg = (t & 3) * 16;
#pragma unroll
          for (int u = 0; u < 2; ++u) {
            us8 hv, mv;
#pragma unroll
            for (int jj = 0; jj < 8; ++jj) {
              unsigned short h, m;
              split2(Sf[(jg + u * 8 + jj) * 68 + i2], h, m);
              hv[jj] = h; mv[jj] = m;
            }
            *(us8*)&wtsL[i2 * 72 + jg + u * 8] = hv;
            *(us8*)&wtsL[4608 + i2 * 72 + jg + u * 8] = mv;
          }
        }
        __syncthreads();
        float* PBl = PB + (size_t)layer * 4194304;
        for (int ph = 0; ph < 2; ++ph) {
          f32x4 a1[4][2];
#pragma unroll
          for (int mf = 0; mf < 4; ++mf)
#pragma unroll
            for (int nf = 0; nf < 2; ++nf) a1[mf][nf] = (f32x4)0.f;
#pragma unroll
          for (int kc = 0; kc < 2; ++kc) {
            short8 vh[2], vm[2];
#pragma unroll
            for (int nf = 0; nf < 2; ++nf) {
              const int pxg = px0 + ph * 128 + w * 32 + nf * 16 + lo16;
              const size_t vb = ((size_t)b * 4096 + pxg) * 64 + kc * 32 + hi4 * 8;
              vh[nf] = *(const short8*)(VBT + vb);
              vm[nf] = *(const short8*)(VBT + 1048576 + vb);
            }
#pragma unroll
            for (int mf = 0; mf < 4; ++mf) {
              const short8 wh = *(const short8*)&wtsL[(mf * 16 + lo16) * 72 + kc * 32 + hi4 * 8];
              const short8 wm = *(const short8*)&wtsL[4608 + (mf * 16 + lo16) * 72 + kc * 32 + hi4 * 8];
#pragma unroll
              for (int nf = 0; nf < 2; ++nf) {
                f32x4 c = a1[mf][nf];
                c = __builtin_amdgcn_mfma_f32_16x16x32_bf16(wh, vh[nf], c, 0, 0, 0);
                c = __builtin_amdgcn_mfma_f32_16x16x32_bf16(wh, vm[nf], c, 0, 0, 0);
                c = __builtin_amdgcn_mfma_f32_16x16x32_bf16(wm, vh[nf], c, 0, 0, 0);
                c = __builtin_amdgcn_mfma_f32_16x16x32_bf16(wm, vm[nf], c, 0, 0, 0);
                a1[mf][nf] = c;
              }
            }
          }
#pragma unroll
          for (int mf = 0; mf < 4; ++mf)
#pragma unroll
            for (int nf = 0; nf < 2; ++nf) {
              const int pxl = w * 32 + nf * 16 + lo16;
              const int i0 = mf * 16 + hi4 * 4;
              us4 hv, mv;
#pragma unroll
              for (int r = 0; r < 4; ++r) {
                unsigned short h, m;
                split2(a1[mf][nf][r], h, m);
                hv[r] = h; mv[r] = m;
              }
              *(us4*)&AbT[pxl * 72 + i0] = hv;
              *(us4*)&AbT[9216 + pxl * 72 + i0] = mv;
            }
          __syncthreads();
          f32x4 a2[16][2];
#pragma unroll
          for (int mf = 0; mf < 16; ++mf)
#pragma unroll
            for (int nf = 0; nf < 2; ++nf) a2[mf][nf] = (f32x4)0.f;
#pragma unroll
          for (int kc = 0; kc < 2; ++kc) {
            short8 abh[2], abm[2];
#pragma unroll
            for (int nf = 0; nf < 2; ++nf) {
              const int pxl = w * 32 + nf * 16 + lo16;
              abh[nf] = *(const short8*)&AbT[pxl * 72 + kc * 32 + hi4 * 8];
              abm[nf] = *(const short8*)&AbT[9216 + pxl * 72 + kc * 32 + hi4 * 8];
            }
#pragma unroll
            for (int mf = 0; mf < 16; ++mf) {
              const int o = mf * 16 + lo16;
              const short8 rh = *(const short8*)(WRH + o * 64 + kc * 32 + hi4 * 8);
              const short8 rm = *(const short8*)(WRH + 16384 + o * 64 + kc * 32 + hi4 * 8);
              const short8 rl = *(const short8*)(WRH + 32768 + o * 64 + kc * 32 + hi4 * 8);
#pragma unroll
              for (int nf = 0; nf < 2; ++nf) {
                f32x4 c = a2[mf][nf];
                c = __builtin_amdgcn_mfma_f32_16x16x32_bf16(rh, abh[nf], c, 0, 0, 0);
                c = __builtin_amdgcn_mfma_f32_16x16x32_bf16(rh, abm[nf], c, 0, 0, 0);
                c = __builtin_amdgcn_mfma_f32_16x16x32_bf16(rm, abh[nf], c, 0, 0, 0);
                c = __builtin_amdgcn_mfma_f32_16x16x32_bf16(rm, abm[nf], c, 0, 0, 0);
                c = __builtin_amdgcn_mfma_f32_16x16x32_bf16(rl, abh[nf], c, 0, 0, 0);
                a2[mf][nf] = c;
              }
            }
          }
#pragma unroll
          for (int mf = 0; mf < 16; ++mf) {
#pragma unroll
            for (int nf = 0; nf < 2; ++nf) {
              const int pxg = px0 + ph * 128 + w * 32 + nf * 16 + lo16;
              const int o0 = mf * 16 + hi4 * 4;
              float4 res;
              if (layer == 0) {
                const float* xp = x + (size_t)b * 16777216 + (size_t)(192 + (pxg >> 6)) * 256
                                  + (192 + (pxg & 63));
#pragma unroll
                for (int r = 0; r < 4; ++r)
                  (&res.x)[r] = a2[mf][nf][r] + br[o0 + r] + xp[(size_t)(o0 + r) * 65536];
              } else {
                const float4 pv = *(const float4*)(Pprev + ((size_t)b * 4096 + pxg) * 256 + o0);
#pragma unroll
                for (int r = 0; r < 4; ++r)
                  (&res.x)[r] = a2[mf][nf][r] + br[o0 + r] + (&pv.x)[r];
              }
              *(float4*)(PBl + ((size_t)b * 4096 + pxg) * 256 + o0) = res;
            }
          }
          __syncthreads();
        }
      }
      gbar(cntA, 64 * (++barSeq));
    }
  }

  // ================= GLOBAL BARRIER + SELECT =================
  gbar(cntG, 256);
  int jsel = 4;
  {
    const int k = t & 63;
    const double fs = fullS[2 * k], fq = fullS[2 * k + 1];
    const double m2 = fs * (1.0 / 65536.0);
    const double v2 = fq * (1.0 / 65536.0) - m2 * m2;
#pragma unroll
    for (int l = 0; l < 4; ++l) {
      const double* ps = patchS + l * 128;
      const double s1 = ps[2 * k], s2 = ps[2 * k + 1];
      const double m1 = s1 * (1.0 / 4096.0);
      const double v1 = s2 * (1.0 / 4096.0) - m1 * m1;
      const double gm = (4096.0 * m1 + 65536.0 * m2) * (1.0 / 69632.0);
      const double d1 = m1 - gm, d2 = m2 - gm;
      const double ssb = 4096.0 * d1 * d1 + 65536.0 * d2 * d2;
      const double ssw = 4096.0 * v1 + 65536.0 * v2;
      const double F = ssb * (69630.0 / ssw);
      const unsigned long long bal = __ballot(F > FCRIT);
      if (2 * __popcll(bal) >= 64 && jsel == 4) jsel = l;
    }
  }
  if (jsel > 0) {
    const float* src = PB + (size_t)(jsel - 1) * 4194304;
    const int b2 = bid >> 6, y = bid & 63;
    float* T = (float*)pool;  // [64][68]
    for (int oc = 0; oc < 4; ++oc) {
      __syncthreads();
      {
        const int pxl = t >> 2, og = (t & 3) * 16;
#pragma unroll
        for (int u = 0; u < 4; ++u) {
          const float4 v = *(const float4*)(src + ((size_t)b2 * 4096 + y * 64 + pxl) * 256
                                            + oc * 64 + og + u * 4);
          *(float4*)&T[pxl * 68 + og + u * 4] = v;
        }
      }
      __syncthreads();
      {
        const int ol = t & 63, pg = t >> 6;
        float* op = out + (size_t)b2 * 16777216 + (size_t)(oc * 64 + ol) * 65536
                    + (size_t)(192 + y) * 256 + 192 + pg * 16;
#pragma unroll
        for (int u4 = 0; u4 < 4; ++u4) {
          float4 v;
#pragma unroll
          for (int r = 0; r < 4; ++r) (&v.x)[r] = T[(pg * 16 + u4 * 4 + r) * 68 + ol];
          *(float4*)(op + u4 * 4) = v;
        }
      }
    }
  }
}

// ---------------- launch ----------------
extern "C" void kernel_launch(void* const* d_in, const int* in_sizes, int n_in,
                              void* d_out, int out_size, void* d_ws, size_t ws_size,
                              hipStream_t stream) {
  const float* x  = (const float*)d_in[0];
  const float* Wq = (const float*)d_in[1];
  const float* bq = (const float*)d_in[2];
  const float* Wk = (const float*)d_in[3];
  const float* bk = (const float*)d_in[4];
  const float* Wv = (const float*)d_in[5];
  const float* bv = (const float*)d_in[6];
  const float* Wr = (const float*)d_in[7];
  const float* br = (const float*)d_in[8];
  const float* Wf = (const float*)d_in[9];
  const float* bf = (const float*)d_in[10];
  float* out = (float*)d_out;
  char* ws = (char*)d_ws;

  (void)hipMemsetAsync(ws, 0, ZERO_BYTES, stream);
  k_wcvt<<<96, 256, 0, stream>>>(Wq, Wk, Wv, Wr, Wf, ws);
  k_mega<<<256, 256, 0, stream>>>(x, bq, bk, bv, br, bf, Wf, out, ws);
}